// Round 20
// baseline (980.370 us; speedup 1.0000x reference)
//
#include <hip/hip_runtime.h>

#define NN 512
#define NM1 511
#define PCT(r, j) pcT[(r) * 13 + (j)]

// X-macros: T4x16(X) expands X(K,M) for K=0..3 (row group), M=0..15 (col)
#define T16(X, K) X(K,0) X(K,1) X(K,2) X(K,3) X(K,4) X(K,5) X(K,6) X(K,7) \
  X(K,8) X(K,9) X(K,10) X(K,11) X(K,12) X(K,13) X(K,14) X(K,15)
#define T4x16(X) T16(X,0) T16(X,1) T16(X,2) T16(X,3)
#define T16S(X) X(0) X(1) X(2) X(3) X(4) X(5) X(6) X(7) \
  X(8) X(9) X(10) X(11) X(12) X(13) X(14) X(15)
#define P8(X, K) X(K,0) X(K,1) X(K,2) X(K,3) X(K,4) X(K,5) X(K,6) X(K,7)
#define P4x8(X) P8(X,0) P8(X,1) P8(X,2) P8(X,3)

// readlane: value of v at (uniform) lane l -> scalar
__device__ __forceinline__ float rdlane(float v, int l) {
  return __uint_as_float(
      (unsigned)__builtin_amdgcn_readlane((int)__float_as_uint(v), l));
}
// fast reciprocal: v_rcp_f32 (~1 ulp); det still multiplies the EXACT pivot
__device__ __forceinline__ float fastrcp(float v) {
  float r;
  asm("v_rcp_f32 %0, %1" : "=v"(r) : "v"(v));
  return r;
}

// One block per matrix (1024 blocks), 1024 threads (16 waves), 1 block/CU via
// LDS pad + waves_per_eu(4,4) -> 128-reg budget.
// r20 = r18 (950us) with SINGLE-WAVE FACTOR: only wave 0 runs the panel
// factor chain (redundant factoring on ~9 waves bought nothing — elapsed is
// bound by one serial chain; it cost ~8.5x panel loads + factor issue).
// Trailing waves post-barrier-B: read p0..p7 from perm (transient), stash
// their OWN Ubuf strip from untouched a-regs (r16's STASHT), fence, per-wave
// U-solve on own strip (r19, within-wave dep only), fence, TUT. 2 barriers/
// panel. Nothing new lives across barriers (r15-r17 spill mode avoided);
// trailing waves never hold pr at all -> lower peak pressure than r18.
__global__ __attribute__((amdgpu_waves_per_eu(4, 4))) __launch_bounds__(1024)
void det_lu_kernel(
    const float* __restrict__ x,
    const float* __restrict__ F,
    float* __restrict__ out) {
  __shared__ __align__(16) float pcT[256 * 13];   // panel cols, row-major pad 13
  __shared__ __align__(16) float lbuf[8 * 256];   // multipliers per step
  __shared__ __align__(16) float Ubuf[8 * 260];   // raw-then-final pivot rows
  __shared__ float livef[256];
  __shared__ int   perm[256];
  __shared__ int   upbuf[256];
  __shared__ int   dnbuf[256];
  __shared__ int   wavecnt[8];
  __shared__ int   totinv;
  __shared__ float ldspad[12100];   // LDS > 80KiB -> exactly 1 block/CU

  const int tid = threadIdx.x;
  const int L   = tid & 63;       // lane
  const int w   = tid >> 6;       // wave, owns cols [16w, 16w+16)

  const float* xrow = x + (size_t)blockIdx.x * NN;

  // keep ldspad referenced (opaque never-true condition)
  if ((int)blockIdx.x < 0) ((volatile float*)ldspad)[tid] = 1.0f;

  // ---- rank the +/-1 pattern: up = x>0 positions, dn = x<=0 positions
  bool pos = false;
  unsigned long long mask = 0;
  if (tid < NN) {
    float xv = xrow[tid];
    pos = xv > 0.0f;
    mask = __ballot(pos);           // waves 0-7 fully active
    if (L == 0) wavecnt[w] = __popcll(mask);
  }
  if (tid == 0) totinv = 0;
  if (tid < 256) livef[tid] = 1.0f;
  __syncthreads();
  if (tid < NN) {
    int base = 0;
    for (int i = 0; i < w; i++) base += wavecnt[i];
    int pbelow = __popcll(mask & ((1ull << L) - 1ull));
    if (pos) upbuf[base + pbelow] = tid;
    else     dnbuf[(64 * w - base) + (L - pbelow)] = tid;
  }
  __syncthreads();

  // ---- gather tile into 64 named scalars: aK_M = sub[L+64K][16w+M]
#define DECLC(M) const int cg##M = dnbuf[16 * w + (M)];
  T16S(DECLC)
  const int rg0 = upbuf[L];
  const int rg1 = upbuf[L + 64];
  const int rg2 = upbuf[L + 128];
  const int rg3 = upbuf[L + 192];
#define DECLA(K, M)                                                         \
  float a##K##_##M = (cg##M == rg##K)                                       \
      ? 0.0f                                                                \
      : F[(size_t)rg##K * NM1 + cg##M - (cg##M > rg##K ? 1 : 0)];
  T4x16(DECLA)

  // ---- seed panel 0: wave 0 (owns cols 0..15) writes PCT[row][0..7]
  if (w == 0) {
#define S0(K, M) if ((M) < 8) PCT(L + 64 * (K), (M)) = a##K##_##M;
    T4x16(S0)
  }
  double det = 1.0;
  __syncthreads();   // barrier A (panel 0 seeded)

  // ======================= panel factor-step machinery =====================
#define DPPMAX(CTRL) {                                                      \
    unsigned _t = (unsigned)__builtin_amdgcn_update_dpp(                    \
        0, (int)key, (CTRL), 0xf, 0xf, false);                              \
    key = key > _t ? key : _t; }
#define BCJ(K, J, S) if ((J) >= (S)) uv##J = rdlane(pr##K##_##J, lp);
#define BCARM(K, S)                                                         \
    if (kp == (K)) { BCJ(K,0,S) BCJ(K,1,S) BCJ(K,2,S) BCJ(K,3,S)            \
                     BCJ(K,4,S) BCJ(K,5,S) BCJ(K,6,S) BCJ(K,7,S) }
#define LSTEP(K, S)                                                         \
    float l##K = ((dead4 >> (K)) & 1u) ? 0.0f : pr##K##_##S * invp;         \
    pr##K##_##S = l##K;
#define UPD(K, J, S)                                                        \
    if ((J) > (S)) pr##K##_##J = fmaf(-l##K, uv##J, pr##K##_##J);
#define UPDJ(J, S) UPD(0,J,S) UPD(1,J,S) UPD(2,J,S) UPD(3,J,S)
#define FSTEP(S) {                                                          \
    unsigned b0 = (dead4 & 1u) ? 0u                                         \
        : ((__float_as_uint(fabsf(pr0_##S)) & 0xFFFFFF00u) | (unsigned)L);  \
    unsigned b1 = (dead4 & 2u) ? 0u                                         \
        : ((__float_as_uint(fabsf(pr1_##S)) & 0xFFFFFF00u) | (unsigned)(L + 64)); \
    unsigned b2 = (dead4 & 4u) ? 0u                                         \
        : ((__float_as_uint(fabsf(pr2_##S)) & 0xFFFFFF00u) | (unsigned)(L + 128)); \
    unsigned b3 = (dead4 & 8u) ? 0u                                         \
        : ((__float_as_uint(fabsf(pr3_##S)) & 0xFFFFFF00u) | (unsigned)(L + 192)); \
    unsigned m01 = b0 > b1 ? b0 : b1, m23 = b2 > b3 ? b2 : b3;              \
    unsigned key = m01 > m23 ? m01 : m23;                                   \
    DPPMAX(0x111) DPPMAX(0x112) DPPMAX(0x114) DPPMAX(0x118)                 \
    DPPMAX(0x142) DPPMAX(0x143)                                             \
    const int pv = __builtin_amdgcn_readlane((int)key, 63) & 255;           \
    const int kp = pv >> 6, lp = pv & 63;                                   \
    if (lp == L) dead4 |= 1u << kp;                                         \
    float uv0 = 0.f, uv1 = 0.f, uv2 = 0.f, uv3 = 0.f;                       \
    float uv4 = 0.f, uv5 = 0.f, uv6 = 0.f, uv7 = 0.f;                       \
    BCARM(0,S) BCARM(1,S) BCARM(2,S) BCARM(3,S)                             \
    const float piv = uv##S;                                                \
    det *= (double)piv;                                                     \
    const float invp = fastrcp(piv);                                        \
    LSTEP(0,S) LSTEP(1,S) LSTEP(2,S) LSTEP(3,S)                             \
    UPDJ(0,S) UPDJ(1,S) UPDJ(2,S) UPDJ(3,S)                                 \
    UPDJ(4,S) UPDJ(5,S) UPDJ(6,S) UPDJ(7,S)                                 \
    lbuf[(S) * 256 + L      ] = l0;                                         \
    lbuf[(S) * 256 + L +  64] = l1;                                         \
    lbuf[(S) * 256 + L + 128] = l2;                                         \
    lbuf[(S) * 256 + L + 192] = l3;                                         \
    if (L == lp) livef[pv] = 0.0f;                                          \
    if (L == 0) perm[P * 8 + (S)] = pv;                                     \
  }

  // ---- trailing: post-barrier stash of raw pivot row T (own 16-col strip)
#define STQW(T, K)                                                          \
    if (L == (p##T & 63)) {                                                 \
      const int ub = (T) * 260 + 16 * w;                                    \
      *reinterpret_cast<float4*>(&Ubuf[ub + 0]) =                           \
          make_float4(a##K##_0, a##K##_1, a##K##_2, a##K##_3);              \
      *reinterpret_cast<float4*>(&Ubuf[ub + 4]) =                           \
          make_float4(a##K##_4, a##K##_5, a##K##_6, a##K##_7);              \
      *reinterpret_cast<float4*>(&Ubuf[ub + 8]) =                           \
          make_float4(a##K##_8, a##K##_9, a##K##_10, a##K##_11);            \
      *reinterpret_cast<float4*>(&Ubuf[ub + 12]) =                          \
          make_float4(a##K##_12, a##K##_13, a##K##_14, a##K##_15);          \
    }
#define STASHT(T) {                                                         \
    const int kpt = p##T >> 6;                                              \
    if (kpt == 0)      { STQW(T, 0) }                                       \
    else if (kpt == 1) { STQW(T, 1) }                                       \
    else if (kpt == 2) { STQW(T, 2) }                                       \
    else               { STQW(T, 3) }                                       \
  }

  // trailing: A_K_M -= sum_t lk_K[t] * U[t][M]
#define TUROW(K, A, B, C, D)                                                \
    a##K##_##A = fmaf(-lk##K, uq.x, a##K##_##A);                            \
    a##K##_##B = fmaf(-lk##K, uq.y, a##K##_##B);                            \
    a##K##_##C = fmaf(-lk##K, uq.z, a##K##_##C);                            \
    a##K##_##D = fmaf(-lk##K, uq.w, a##K##_##D);
#define TUQ(A, B, C, D)                                                     \
    TUROW(0, A, B, C, D) TUROW(1, A, B, C, D)                               \
    TUROW(2, A, B, C, D) TUROW(3, A, B, C, D)

  // ---- panel loop (barriers at workgroup-uniform top level ONLY)
#pragma unroll 1
  for (int P = 0; P < 32; P++) {
    const bool trailing = (2 * w + 1 > P);       // wave-uniform

    if (w == 0) {
      // ---- factor panel P in registers (serial chain, wave 0 only)
#define LDP(K, J) float pr##K##_##J = PCT(L + 64 * (K), (J));
      P4x8(LDP)
      unsigned dead4 = 0u;
      FSTEP(0) FSTEP(1) FSTEP(2) FSTEP(3)
      FSTEP(4) FSTEP(5) FSTEP(6) FSTEP(7)
    }
    __syncthreads();   // barrier B: lbuf/livef/perm visible

    if (trailing) {
      // pivot ids (uniform LDS reads; transient)
      const int p0 = perm[P * 8 + 0], p1 = perm[P * 8 + 1];
      const int p2 = perm[P * 8 + 2], p3 = perm[P * 8 + 3];
      const int p4 = perm[P * 8 + 4], p5 = perm[P * 8 + 5];
      const int p6 = perm[P * 8 + 6], p7 = perm[P * 8 + 7];
      // stash raw pivot rows (untouched a-regs) into my OWN Ubuf strip
      STASHT(0) STASHT(1) STASHT(2) STASHT(3)
      STASHT(4) STASHT(5) STASHT(6) STASHT(7)
      // within-wave ordering: stash writes complete before U-solve reads
      asm volatile("s_waitcnt lgkmcnt(0)" ::: "memory");

      // ---- per-wave U-solve on OWN 16-col strip (lanes 0-15)
      if (L < 16) {
        const int jb = 16 * w + L;
        float u[8];
#pragma unroll
        for (int t = 0; t < 8; t++) {
          const int pt = perm[P * 8 + t];
          float acc = Ubuf[t * 260 + jb];        // raw (stashed above)
#pragma unroll
          for (int s2 = 0; s2 < t; s2++)
            acc = fmaf(-lbuf[s2 * 256 + pt], u[s2], acc);
          u[t] = acc;
          Ubuf[t * 260 + jb] = acc;              // final
        }
      }
      // within-wave ordering: U-solve writes complete before TUT reads
      asm volatile("s_waitcnt lgkmcnt(0)" ::: "memory");

      // ---- rank-8 trailing update (reads own Ubuf strip only)
#pragma unroll 1
      for (int t = 0; t < 8; t++) {
        const int lb = t * 256 + L;
        const float lk0 = lbuf[lb];
        const float lk1 = lbuf[lb + 64];
        const float lk2 = lbuf[lb + 128];
        const float lk3 = lbuf[lb + 192];
        const float* ub = &Ubuf[t * 260 + 16 * w];
        { const float4 uq = *reinterpret_cast<const float4*>(ub + 0);
          TUQ(0, 1, 2, 3) }
        { const float4 uq = *reinterpret_cast<const float4*>(ub + 4);
          TUQ(4, 5, 6, 7) }
        { const float4 uq = *reinterpret_cast<const float4*>(ub + 8);
          TUQ(8, 9, 10, 11) }
        { const float4 uq = *reinterpret_cast<const float4*>(ub + 12);
          TUQ(12, 13, 14, 15) }
      }
    }
    // -------- seed next panel --------
    {
      const int wstar = (P + 1) >> 1, h = (P + 1) & 1;
      if (P < 31 && w == wstar) {
        const float lv0 = livef[L];
        const float lv1 = livef[L + 64];
        const float lv2 = livef[L + 128];
        const float lv3 = livef[L + 192];
#define SEa(K, M) if ((M) < 8)  PCT(L + 64*(K), (M))     = a##K##_##M * lv##K;
#define SEb(K, M) if ((M) >= 8) PCT(L + 64*(K), (M) - 8) = a##K##_##M * lv##K;
        if (h == 0) { T4x16(SEa) }
        else        { T4x16(SEb) }
      }
    }
    __syncthreads();   // barrier A: next panel seeded
  }

  // ---- permutation parity via parallel inversion count (1024-thread map)
  int myinv = 0;
  {
    const int i0 = tid & 255;
    const int cbase = (tid >> 8) * 64;
    const int pi = perm[i0];
#pragma unroll 8
    for (int j = 0; j < 64; j++) {
      int jj = cbase + j;
      if (jj > i0 && perm[jj] < pi) myinv++;
    }
  }
#pragma unroll
  for (int off = 32; off; off >>= 1) myinv += __shfl_xor(myinv, off);
  if (L == 0) atomicAdd(&totinv, myinv);
  __syncthreads();
  if (tid == 0) out[blockIdx.x] = (float)((totinv & 1) ? -det : det);
}

extern "C" void kernel_launch(void* const* d_in, const int* in_sizes, int n_in,
                              void* d_out, int out_size, void* d_ws, size_t ws_size,
                              hipStream_t stream) {
  const float* x = (const float*)d_in[0];   // (1024, 512) fp32
  const float* F = (const float*)d_in[1];   // (512*512-512,) fp32
  float* out = (float*)d_out;               // (1024,) fp32
  const int B = out_size;                   // 1024
  hipLaunchKernelGGL(det_lu_kernel, dim3(B), dim3(1024), 0, stream, x, F, out);
}

// Round 21
// 947.490 us; speedup vs baseline: 1.0347x; 1.0347x over previous
//
#include <hip/hip_runtime.h>

#define NN 512
#define NM1 511
#define PCT(r, j) pcT[(r) * 13 + (j)]

// X-macros: T4x16(X) expands X(K,M) for K=0..3 (row group), M=0..15 (col)
#define T16(X, K) X(K,0) X(K,1) X(K,2) X(K,3) X(K,4) X(K,5) X(K,6) X(K,7) \
  X(K,8) X(K,9) X(K,10) X(K,11) X(K,12) X(K,13) X(K,14) X(K,15)
#define T4x16(X) T16(X,0) T16(X,1) T16(X,2) T16(X,3)
#define T16S(X) X(0) X(1) X(2) X(3) X(4) X(5) X(6) X(7) \
  X(8) X(9) X(10) X(11) X(12) X(13) X(14) X(15)
#define P8(X, K) X(K,0) X(K,1) X(K,2) X(K,3) X(K,4) X(K,5) X(K,6) X(K,7)
#define P4x8(X) P8(X,0) P8(X,1) P8(X,2) P8(X,3)

// readlane: value of v at (uniform) lane l -> scalar
__device__ __forceinline__ float rdlane(float v, int l) {
  return __uint_as_float(
      (unsigned)__builtin_amdgcn_readlane((int)__float_as_uint(v), l));
}
// fast reciprocal: v_rcp_f32 (~1 ulp); det still multiplies the EXACT pivot
__device__ __forceinline__ float fastrcp(float v) {
  float r;
  asm("v_rcp_f32 %0, %1" : "=v"(r) : "v"(v));
  return r;
}

// One block per matrix (1024 blocks), 1024 THREADS (16 waves), 1 block/CU via
// LDS pad + waves_per_eu(4,4) -> 4 waves/SIMD, 128-reg/thread budget.
// r21 = byte-exact r18 (950us verified best: redundant factor on live waves,
// 4-wave U-solve, 3 uniform barriers, fastrcp) + ONE change: trailing t-loop
// "#pragma unroll 2" so iteration t+1's 8 LDS reads issue under iteration t's
// 64 FMAs (unroll 1 exposed ~120cy ds_read latency per iteration; cycle
// accounting showed ~2x slack vs issue counts). Transients grow only WITHIN
// the trailing region — nothing new crosses a barrier (the r15-r20-proven
// spill trigger). r19/r20 variants (per-wave U-solve, single-wave factor)
// both regressed; r18's phase structure is the verified optimum.
__global__ __attribute__((amdgpu_waves_per_eu(4, 4))) __launch_bounds__(1024)
void det_lu_kernel(
    const float* __restrict__ x,
    const float* __restrict__ F,
    float* __restrict__ out) {
  __shared__ __align__(16) float pcT[256 * 13];   // panel cols, row-major pad 13
  __shared__ __align__(16) float lbuf[8 * 256];   // multipliers per step
  __shared__ __align__(16) float Ubuf[8 * 260];   // raw-then-final pivot rows
  __shared__ float livef[256];
  __shared__ int   perm[256];
  __shared__ int   upbuf[256];
  __shared__ int   dnbuf[256];
  __shared__ int   wavecnt[8];
  __shared__ int   totinv;
  __shared__ float ldspad[12100];   // LDS > 80KiB -> exactly 1 block/CU

  const int tid = threadIdx.x;
  const int L   = tid & 63;       // lane
  const int w   = tid >> 6;       // wave, owns cols [16w, 16w+16)

  const float* xrow = x + (size_t)blockIdx.x * NN;

  // keep ldspad referenced (opaque never-true condition)
  if ((int)blockIdx.x < 0) ((volatile float*)ldspad)[tid] = 1.0f;

  // ---- rank the +/-1 pattern: up = x>0 positions, dn = x<=0 positions
  bool pos = false;
  unsigned long long mask = 0;
  if (tid < NN) {
    float xv = xrow[tid];
    pos = xv > 0.0f;
    mask = __ballot(pos);           // waves 0-7 fully active
    if (L == 0) wavecnt[w] = __popcll(mask);
  }
  if (tid == 0) totinv = 0;
  if (tid < 256) livef[tid] = 1.0f;
  __syncthreads();
  if (tid < NN) {
    int base = 0;
    for (int i = 0; i < w; i++) base += wavecnt[i];
    int pbelow = __popcll(mask & ((1ull << L) - 1ull));
    if (pos) upbuf[base + pbelow] = tid;
    else     dnbuf[(64 * w - base) + (L - pbelow)] = tid;
  }
  __syncthreads();

  // ---- gather tile into 64 named scalars: aK_M = sub[L+64K][16w+M]
#define DECLC(M) const int cg##M = dnbuf[16 * w + (M)];
  T16S(DECLC)
  const int rg0 = upbuf[L];
  const int rg1 = upbuf[L + 64];
  const int rg2 = upbuf[L + 128];
  const int rg3 = upbuf[L + 192];
#define DECLA(K, M)                                                         \
  float a##K##_##M = (cg##M == rg##K)                                       \
      ? 0.0f                                                                \
      : F[(size_t)rg##K * NM1 + cg##M - (cg##M > rg##K ? 1 : 0)];
  T4x16(DECLA)

  // ---- seed panel 0: wave 0 (owns cols 0..15) writes PCT[row][0..7]
  if (w == 0) {
#define S0(K, M) if ((M) < 8) PCT(L + 64 * (K), (M)) = a##K##_##M;
    T4x16(S0)
  }
  double det = 1.0;
  __syncthreads();   // barrier A (panel 0 seeded)

  // ======================= panel factor-step machinery =====================
#define DPPMAX(CTRL) {                                                      \
    unsigned _t = (unsigned)__builtin_amdgcn_update_dpp(                    \
        0, (int)key, (CTRL), 0xf, 0xf, false);                              \
    key = key > _t ? key : _t; }
#define BCJ(K, J, S) if ((J) >= (S)) uv##J = rdlane(pr##K##_##J, lp);
#define BCARM(K, S)                                                         \
    if (kp == (K)) { BCJ(K,0,S) BCJ(K,1,S) BCJ(K,2,S) BCJ(K,3,S)            \
                     BCJ(K,4,S) BCJ(K,5,S) BCJ(K,6,S) BCJ(K,7,S) }
#define LSTEP(K, S)                                                         \
    float l##K = ((dead4 >> (K)) & 1u) ? 0.0f : pr##K##_##S * invp;         \
    pr##K##_##S = l##K;
#define UPD(K, J, S)                                                        \
    if ((J) > (S)) pr##K##_##J = fmaf(-l##K, uv##J, pr##K##_##J);
#define UPDJ(J, S) UPD(0,J,S) UPD(1,J,S) UPD(2,J,S) UPD(3,J,S)
#define STQ(K, Q, M0, M1, M2, M3)                                           \
    if (kp == (K)) *reinterpret_cast<float4*>(&Ubuf[sb + 4 * (Q)]) =        \
        make_float4(a##K##_##M0, a##K##_##M1, a##K##_##M2, a##K##_##M3);
#define STHK(K)                                                             \
    STQ(K,0,0,1,2,3) STQ(K,1,4,5,6,7)                                       \
    STQ(K,2,8,9,10,11) STQ(K,3,12,13,14,15)
#define FSTEP(S) {                                                          \
    unsigned b0 = (dead4 & 1u) ? 0u                                         \
        : ((__float_as_uint(fabsf(pr0_##S)) & 0xFFFFFF00u) | (unsigned)L);  \
    unsigned b1 = (dead4 & 2u) ? 0u                                         \
        : ((__float_as_uint(fabsf(pr1_##S)) & 0xFFFFFF00u) | (unsigned)(L + 64)); \
    unsigned b2 = (dead4 & 4u) ? 0u                                         \
        : ((__float_as_uint(fabsf(pr2_##S)) & 0xFFFFFF00u) | (unsigned)(L + 128)); \
    unsigned b3 = (dead4 & 8u) ? 0u                                         \
        : ((__float_as_uint(fabsf(pr3_##S)) & 0xFFFFFF00u) | (unsigned)(L + 192)); \
    unsigned m01 = b0 > b1 ? b0 : b1, m23 = b2 > b3 ? b2 : b3;              \
    unsigned key = m01 > m23 ? m01 : m23;                                   \
    DPPMAX(0x111) DPPMAX(0x112) DPPMAX(0x114) DPPMAX(0x118)                 \
    DPPMAX(0x142) DPPMAX(0x143)                                             \
    const int pv = __builtin_amdgcn_readlane((int)key, 63) & 255;           \
    const int kp = pv >> 6, lp = pv & 63;                                   \
    if (lp == L) dead4 |= 1u << kp;                                         \
    float uv0 = 0.f, uv1 = 0.f, uv2 = 0.f, uv3 = 0.f;                       \
    float uv4 = 0.f, uv5 = 0.f, uv6 = 0.f, uv7 = 0.f;                       \
    BCARM(0,S) BCARM(1,S) BCARM(2,S) BCARM(3,S)                             \
    const float piv = uv##S;                                                \
    det *= (double)piv;                                                     \
    const float invp = fastrcp(piv);                                        \
    LSTEP(0,S) LSTEP(1,S) LSTEP(2,S) LSTEP(3,S)                             \
    UPDJ(0,S) UPDJ(1,S) UPDJ(2,S) UPDJ(3,S)                                 \
    UPDJ(4,S) UPDJ(5,S) UPDJ(6,S) UPDJ(7,S)                                 \
    if (w == 0) {                                                           \
      lbuf[(S) * 256 + L      ] = l0;                                       \
      lbuf[(S) * 256 + L +  64] = l1;                                       \
      lbuf[(S) * 256 + L + 128] = l2;                                       \
      lbuf[(S) * 256 + L + 192] = l3;                                       \
      if (L == lp) livef[pv] = 0.0f;                                        \
      if (L == 0) perm[P * 8 + (S)] = pv;                                   \
    }                                                                       \
    if (trailing && L == lp) {                                              \
      const int sb = (S) * 260 + 16 * w;                                    \
      STHK(0) STHK(1) STHK(2) STHK(3)                                       \
    }                                                                       \
  }

  // trailing: A_K_M -= sum_t lk_K[t] * U[t][M]
#define TUROW(K, A, B, C, D)                                                \
    a##K##_##A = fmaf(-lk##K, uq.x, a##K##_##A);                            \
    a##K##_##B = fmaf(-lk##K, uq.y, a##K##_##B);                            \
    a##K##_##C = fmaf(-lk##K, uq.z, a##K##_##C);                            \
    a##K##_##D = fmaf(-lk##K, uq.w, a##K##_##D);
#define TUQ(A, B, C, D)                                                     \
    TUROW(0, A, B, C, D) TUROW(1, A, B, C, D)                               \
    TUROW(2, A, B, C, D) TUROW(3, A, B, C, D)

  // ---- panel loop (barriers at workgroup-uniform top level ONLY)
#pragma unroll 1
  for (int P = 0; P < 32; P++) {
    const bool trailing  = (2 * w + 1 > P);      // wave-uniform
    const bool factoring = trailing || (w == 0); // wave-uniform

    if (factoring) {
      // load panel into regs (redundant per-wave copy of all 256 rows)
#define LDP(K, J) float pr##K##_##J = PCT(L + 64 * (K), (J));
      P4x8(LDP)
      unsigned dead4 = 0u;
      // 8 in-register column-steps: no barriers, no bpermute
      FSTEP(0) FSTEP(1) FSTEP(2) FSTEP(3)
      FSTEP(4) FSTEP(5) FSTEP(6) FSTEP(7)
    }
    __syncthreads();   // barrier B: lbuf/livef/perm + Ubuf raw stash visible

    // -------- U-solve: Ubuf[t][j] = raw[t][j] - sum_{s<t} l[s][p_t]*U[s][j]
    if (tid < 256) {
      const int j = tid;
      float u[8];
#pragma unroll
      for (int t = 0; t < 8; t++) {
        int pt = perm[P * 8 + t];
        float acc = Ubuf[t * 260 + j];           // raw (stashed in factor)
#pragma unroll
        for (int s2 = 0; s2 < t; s2++) acc = fmaf(-lbuf[s2 * 256 + pt], u[s2], acc);
        u[t] = acc;
        Ubuf[t * 260 + j] = acc;                 // final
      }
    }
    __syncthreads();   // barrier C: Ubuf final visible

    // -------- rank-8 trailing update + seed next panel --------
    if (trailing) {
#pragma unroll 2
      for (int t = 0; t < 8; t++) {
        const int lb = t * 256 + L;
        const float lk0 = lbuf[lb];
        const float lk1 = lbuf[lb + 64];
        const float lk2 = lbuf[lb + 128];
        const float lk3 = lbuf[lb + 192];
        const float* ub = &Ubuf[t * 260 + 16 * w];
        { const float4 uq = *reinterpret_cast<const float4*>(ub + 0);
          TUQ(0, 1, 2, 3) }
        { const float4 uq = *reinterpret_cast<const float4*>(ub + 4);
          TUQ(4, 5, 6, 7) }
        { const float4 uq = *reinterpret_cast<const float4*>(ub + 8);
          TUQ(8, 9, 10, 11) }
        { const float4 uq = *reinterpret_cast<const float4*>(ub + 12);
          TUQ(12, 13, 14, 15) }
      }
    }
    {
      const int wstar = (P + 1) >> 1, h = (P + 1) & 1;
      if (P < 31 && w == wstar) {
        const float lv0 = livef[L];
        const float lv1 = livef[L + 64];
        const float lv2 = livef[L + 128];
        const float lv3 = livef[L + 192];
#define SEa(K, M) if ((M) < 8)  PCT(L + 64*(K), (M))     = a##K##_##M * lv##K;
#define SEb(K, M) if ((M) >= 8) PCT(L + 64*(K), (M) - 8) = a##K##_##M * lv##K;
        if (h == 0) { T4x16(SEa) }
        else        { T4x16(SEb) }
      }
    }
    __syncthreads();   // barrier A: next panel seeded
  }

  // ---- permutation parity via parallel inversion count (1024-thread map)
  int myinv = 0;
  {
    const int i0 = tid & 255;
    const int cbase = (tid >> 8) * 64;
    const int pi = perm[i0];
#pragma unroll 8
    for (int j = 0; j < 64; j++) {
      int jj = cbase + j;
      if (jj > i0 && perm[jj] < pi) myinv++;
    }
  }
#pragma unroll
  for (int off = 32; off; off >>= 1) myinv += __shfl_xor(myinv, off);
  if (L == 0) atomicAdd(&totinv, myinv);
  __syncthreads();
  if (tid == 0) out[blockIdx.x] = (float)((totinv & 1) ? -det : det);
}

extern "C" void kernel_launch(void* const* d_in, const int* in_sizes, int n_in,
                              void* d_out, int out_size, void* d_ws, size_t ws_size,
                              hipStream_t stream) {
  const float* x = (const float*)d_in[0];   // (1024, 512) fp32
  const float* F = (const float*)d_in[1];   // (512*512-512,) fp32
  float* out = (float*)d_out;               // (1024,) fp32
  const int B = out_size;                   // 1024
  hipLaunchKernelGGL(det_lu_kernel, dim3(B), dim3(1024), 0, stream, x, F, out);
}

// Round 22
// 921.770 us; speedup vs baseline: 1.0636x; 1.0279x over previous
//
#include <hip/hip_runtime.h>

#define NN 512
#define NM1 511
#define PCT(r, j) pcT[(r) * 13 + (j)]

// X-macros: T4x16(X) expands X(K,M) for K=0..3 (row group), M=0..15 (col)
#define T16(X, K) X(K,0) X(K,1) X(K,2) X(K,3) X(K,4) X(K,5) X(K,6) X(K,7) \
  X(K,8) X(K,9) X(K,10) X(K,11) X(K,12) X(K,13) X(K,14) X(K,15)
#define T4x16(X) T16(X,0) T16(X,1) T16(X,2) T16(X,3)
#define T16S(X) X(0) X(1) X(2) X(3) X(4) X(5) X(6) X(7) \
  X(8) X(9) X(10) X(11) X(12) X(13) X(14) X(15)
#define P8(X, K) X(K,0) X(K,1) X(K,2) X(K,3) X(K,4) X(K,5) X(K,6) X(K,7)
#define P4x8(X) P8(X,0) P8(X,1) P8(X,2) P8(X,3)

// readlane: value of v at (uniform) lane l -> scalar
__device__ __forceinline__ float rdlane(float v, int l) {
  return __uint_as_float(
      (unsigned)__builtin_amdgcn_readlane((int)__float_as_uint(v), l));
}
// fast reciprocal: v_rcp_f32 (~1 ulp); det still multiplies the EXACT pivot
__device__ __forceinline__ float fastrcp(float v) {
  float r;
  asm("v_rcp_f32 %0, %1" : "=v"(r) : "v"(v));
  return r;
}

// One block per matrix (1024 blocks), 1024 threads (16 waves), 1 block/CU via
// LDS pad + waves_per_eu(4,4) -> 128-reg budget.
// r22 = LU LOOKAHEAD on the converged r18 structure (947-950us):
//  Phase 1: wave 0 factors panel P (lbufD[b], perm, livef)  CONCURRENT with
//           other live waves' deferred TUT of panel P-1 (lbufD[b^1]/UbufD[b^1],
//           double-buffered LDS so readers/writers are disjoint).
//  Phase 2: trailing waves stash raw pivot rows post-barrier (r20) + per-wave
//           U-solve on own strip (r19, within-wave fences); seed wave
//           wstar=(P+1)>>1 runs its TUT(P) EARLY and seeds panel P+1.
//  Skip rule: wave w skips phase-1 TUT when w == P>>1 (applied early as seed).
// 2 uniform barriers/iter; nothing new lives across barriers (spill trigger
// from r15-r17 avoided); all phase bodies are r18/r19/r20-verified pieces.
__global__ __attribute__((amdgpu_waves_per_eu(4, 4))) __launch_bounds__(1024)
void det_lu_kernel(
    const float* __restrict__ x,
    const float* __restrict__ F,
    float* __restrict__ out) {
  __shared__ __align__(16) float pcT[256 * 13];   // panel cols, row-major pad 13
  __shared__ __align__(16) float lbufD[2][8 * 256]; // multipliers (dbuf)
  __shared__ __align__(16) float UbufD[2][8 * 260]; // pivot rows (dbuf)
  __shared__ float livef[256];
  __shared__ int   perm[256];
  __shared__ int   upbuf[256];
  __shared__ int   dnbuf[256];
  __shared__ int   wavecnt[8];
  __shared__ int   totinv;
  __shared__ float ldspad[7900];    // LDS total > 80KiB -> exactly 1 block/CU

  const int tid = threadIdx.x;
  const int L   = tid & 63;       // lane
  const int w   = tid >> 6;       // wave, owns cols [16w, 16w+16)

  const float* xrow = x + (size_t)blockIdx.x * NN;

  // keep ldspad referenced (opaque never-true condition)
  if ((int)blockIdx.x < 0) ((volatile float*)ldspad)[tid] = 1.0f;

  // ---- rank the +/-1 pattern: up = x>0 positions, dn = x<=0 positions
  bool pos = false;
  unsigned long long mask = 0;
  if (tid < NN) {
    float xv = xrow[tid];
    pos = xv > 0.0f;
    mask = __ballot(pos);           // waves 0-7 fully active
    if (L == 0) wavecnt[w] = __popcll(mask);
  }
  if (tid == 0) totinv = 0;
  if (tid < 256) livef[tid] = 1.0f;
  __syncthreads();
  if (tid < NN) {
    int base = 0;
    for (int i = 0; i < w; i++) base += wavecnt[i];
    int pbelow = __popcll(mask & ((1ull << L) - 1ull));
    if (pos) upbuf[base + pbelow] = tid;
    else     dnbuf[(64 * w - base) + (L - pbelow)] = tid;
  }
  __syncthreads();

  // ---- gather tile into 64 named scalars: aK_M = sub[L+64K][16w+M]
#define DECLC(M) const int cg##M = dnbuf[16 * w + (M)];
  T16S(DECLC)
  const int rg0 = upbuf[L];
  const int rg1 = upbuf[L + 64];
  const int rg2 = upbuf[L + 128];
  const int rg3 = upbuf[L + 192];
#define DECLA(K, M)                                                         \
  float a##K##_##M = (cg##M == rg##K)                                       \
      ? 0.0f                                                                \
      : F[(size_t)rg##K * NM1 + cg##M - (cg##M > rg##K ? 1 : 0)];
  T4x16(DECLA)

  // ---- seed panel 0: wave 0 (owns cols 0..15) writes PCT[row][0..7]
  if (w == 0) {
#define S0(K, M) if ((M) < 8) PCT(L + 64 * (K), (M)) = a##K##_##M;
    T4x16(S0)
  }
  double det = 1.0;
  __syncthreads();   // barrier A (panel 0 seeded)

  // ======================= panel factor-step machinery (wave 0) ===========
#define DPPMAX(CTRL) {                                                      \
    unsigned _t = (unsigned)__builtin_amdgcn_update_dpp(                    \
        0, (int)key, (CTRL), 0xf, 0xf, false);                              \
    key = key > _t ? key : _t; }
#define BCJ(K, J, S) if ((J) >= (S)) uv##J = rdlane(pr##K##_##J, lp);
#define BCARM(K, S)                                                         \
    if (kp == (K)) { BCJ(K,0,S) BCJ(K,1,S) BCJ(K,2,S) BCJ(K,3,S)            \
                     BCJ(K,4,S) BCJ(K,5,S) BCJ(K,6,S) BCJ(K,7,S) }
#define LSTEP(K, S)                                                         \
    float l##K = ((dead4 >> (K)) & 1u) ? 0.0f : pr##K##_##S * invp;         \
    pr##K##_##S = l##K;
#define UPD(K, J, S)                                                        \
    if ((J) > (S)) pr##K##_##J = fmaf(-l##K, uv##J, pr##K##_##J);
#define UPDJ(J, S) UPD(0,J,S) UPD(1,J,S) UPD(2,J,S) UPD(3,J,S)
#define FSTEP(S) {                                                          \
    unsigned b0 = (dead4 & 1u) ? 0u                                         \
        : ((__float_as_uint(fabsf(pr0_##S)) & 0xFFFFFF00u) | (unsigned)L);  \
    unsigned b1 = (dead4 & 2u) ? 0u                                         \
        : ((__float_as_uint(fabsf(pr1_##S)) & 0xFFFFFF00u) | (unsigned)(L + 64)); \
    unsigned b2 = (dead4 & 4u) ? 0u                                         \
        : ((__float_as_uint(fabsf(pr2_##S)) & 0xFFFFFF00u) | (unsigned)(L + 128)); \
    unsigned b3 = (dead4 & 8u) ? 0u                                         \
        : ((__float_as_uint(fabsf(pr3_##S)) & 0xFFFFFF00u) | (unsigned)(L + 192)); \
    unsigned m01 = b0 > b1 ? b0 : b1, m23 = b2 > b3 ? b2 : b3;              \
    unsigned key = m01 > m23 ? m01 : m23;                                   \
    DPPMAX(0x111) DPPMAX(0x112) DPPMAX(0x114) DPPMAX(0x118)                 \
    DPPMAX(0x142) DPPMAX(0x143)                                             \
    const int pv = __builtin_amdgcn_readlane((int)key, 63) & 255;           \
    const int kp = pv >> 6, lp = pv & 63;                                   \
    if (lp == L) dead4 |= 1u << kp;                                         \
    float uv0 = 0.f, uv1 = 0.f, uv2 = 0.f, uv3 = 0.f;                       \
    float uv4 = 0.f, uv5 = 0.f, uv6 = 0.f, uv7 = 0.f;                       \
    BCARM(0,S) BCARM(1,S) BCARM(2,S) BCARM(3,S)                             \
    const float piv = uv##S;                                                \
    det *= (double)piv;                                                     \
    const float invp = fastrcp(piv);                                        \
    LSTEP(0,S) LSTEP(1,S) LSTEP(2,S) LSTEP(3,S)                             \
    UPDJ(0,S) UPDJ(1,S) UPDJ(2,S) UPDJ(3,S)                                 \
    UPDJ(4,S) UPDJ(5,S) UPDJ(6,S) UPDJ(7,S)                                 \
    lbP[(S) * 256 + L      ] = l0;                                          \
    lbP[(S) * 256 + L +  64] = l1;                                          \
    lbP[(S) * 256 + L + 128] = l2;                                          \
    lbP[(S) * 256 + L + 192] = l3;                                          \
    if (L == lp) livef[pv] = 0.0f;                                          \
    if (L == 0) perm[P * 8 + (S)] = pv;                                     \
  }

  // ---- post-barrier stash of raw pivot row T (own 16-col strip, into ubP)
#define STQW(T, K)                                                          \
    if (L == (p##T & 63)) {                                                 \
      float* ubw = &ubP[(T) * 260 + 16 * w];                                \
      *reinterpret_cast<float4*>(ubw + 0) =                                 \
          make_float4(a##K##_0, a##K##_1, a##K##_2, a##K##_3);              \
      *reinterpret_cast<float4*>(ubw + 4) =                                 \
          make_float4(a##K##_4, a##K##_5, a##K##_6, a##K##_7);              \
      *reinterpret_cast<float4*>(ubw + 8) =                                 \
          make_float4(a##K##_8, a##K##_9, a##K##_10, a##K##_11);            \
      *reinterpret_cast<float4*>(ubw + 12) =                                \
          make_float4(a##K##_12, a##K##_13, a##K##_14, a##K##_15);          \
    }
#define STASHT(T) {                                                         \
    const int kpt = p##T >> 6;                                              \
    if (kpt == 0)      { STQW(T, 0) }                                       \
    else if (kpt == 1) { STQW(T, 1) }                                       \
    else if (kpt == 2) { STQW(T, 2) }                                       \
    else               { STQW(T, 3) }                                       \
  }

  // trailing update body: A_K_M -= sum_t lk_K[t] * U[t][M]
#define TUROW(K, A, B, C, D)                                                \
    a##K##_##A = fmaf(-lk##K, uq.x, a##K##_##A);                            \
    a##K##_##B = fmaf(-lk##K, uq.y, a##K##_##B);                            \
    a##K##_##C = fmaf(-lk##K, uq.z, a##K##_##C);                            \
    a##K##_##D = fmaf(-lk##K, uq.w, a##K##_##D);
#define TUQ(A, B, C, D)                                                     \
    TUROW(0, A, B, C, D) TUROW(1, A, B, C, D)                               \
    TUROW(2, A, B, C, D) TUROW(3, A, B, C, D)
#define TUTLOOP(LB_, UB_)                                                   \
    _Pragma("unroll 2")                                                     \
    for (int t = 0; t < 8; t++) {                                           \
      const float lk0 = (LB_)[t * 256 + L];                                 \
      const float lk1 = (LB_)[t * 256 + L + 64];                            \
      const float lk2 = (LB_)[t * 256 + L + 128];                           \
      const float lk3 = (LB_)[t * 256 + L + 192];                           \
      const float* ub_ = &(UB_)[t * 260 + 16 * w];                          \
      { const float4 uq = *reinterpret_cast<const float4*>(ub_ + 0);        \
        TUQ(0, 1, 2, 3) }                                                   \
      { const float4 uq = *reinterpret_cast<const float4*>(ub_ + 4);        \
        TUQ(4, 5, 6, 7) }                                                   \
      { const float4 uq = *reinterpret_cast<const float4*>(ub_ + 8);        \
        TUQ(8, 9, 10, 11) }                                                 \
      { const float4 uq = *reinterpret_cast<const float4*>(ub_ + 12);       \
        TUQ(12, 13, 14, 15) }                                               \
    }

  // ---- panel loop with lookahead (barriers at uniform top level ONLY)
#pragma unroll 1
  for (int P = 0; P < 32; P++) {
    const int bsel = P & 1;
    float* const lbP = lbufD[bsel];          // panel P multipliers
    float* const ubP = UbufD[bsel];          // panel P pivot rows
    const float* const lbQ = lbufD[bsel ^ 1]; // panel P-1
    const float* const ubQ = UbufD[bsel ^ 1];
    const bool trailingP = (2 * w + 1 > P);  // wave-uniform: live at P
    const bool trailPrev =                   // deferred TUT(P-1) pending
        (P > 0) && (2 * w + 1 > P - 1) && (w != (P >> 1));

    // -------- phase 1: factor(P) on wave 0  ||  TUT(P-1) on other waves
    if (w == 0) {
#define LDP(K, J) float pr##K##_##J = PCT(L + 64 * (K), (J));
      P4x8(LDP)
      unsigned dead4 = 0u;
      FSTEP(0) FSTEP(1) FSTEP(2) FSTEP(3)
      FSTEP(4) FSTEP(5) FSTEP(6) FSTEP(7)
    } else if (trailPrev) {
      TUTLOOP(lbQ, ubQ)
    }
    __syncthreads();   // barrier B: lbP/livef/perm visible; TUT(P-1) done

    // -------- phase 2: stash + per-wave U-solve (trailing waves);
    //                   seed wave: early TUT(P) + seed panel P+1
    if (trailingP) {
      const int p0 = perm[P * 8 + 0], p1 = perm[P * 8 + 1];
      const int p2 = perm[P * 8 + 2], p3 = perm[P * 8 + 3];
      const int p4 = perm[P * 8 + 4], p5 = perm[P * 8 + 5];
      const int p6 = perm[P * 8 + 6], p7 = perm[P * 8 + 7];
      STASHT(0) STASHT(1) STASHT(2) STASHT(3)
      STASHT(4) STASHT(5) STASHT(6) STASHT(7)
      asm volatile("s_waitcnt lgkmcnt(0)" ::: "memory");
      if (L < 16) {            // per-wave U-solve on OWN 16-col strip
        const int jb = 16 * w + L;
        float u[8];
#pragma unroll
        for (int t = 0; t < 8; t++) {
          const int pt = perm[P * 8 + t];
          float acc = ubP[t * 260 + jb];
#pragma unroll
          for (int s2 = 0; s2 < t; s2++)
            acc = fmaf(-lbP[s2 * 256 + pt], u[s2], acc);
          u[t] = acc;
          ubP[t * 260 + jb] = acc;
        }
      }
      asm volatile("s_waitcnt lgkmcnt(0)" ::: "memory");
    }
    {
      const int wstar = (P + 1) >> 1, h = (P + 1) & 1;
      if (P < 31 && w == wstar) {
        TUTLOOP(lbP, ubP)      // early TUT(P) — this wave is always trailingP
        const float lv0 = livef[L];
        const float lv1 = livef[L + 64];
        const float lv2 = livef[L + 128];
        const float lv3 = livef[L + 192];
#define SEa(K, M) if ((M) < 8)  PCT(L + 64*(K), (M))     = a##K##_##M * lv##K;
#define SEb(K, M) if ((M) >= 8) PCT(L + 64*(K), (M) - 8) = a##K##_##M * lv##K;
        if (h == 0) { T4x16(SEa) }
        else        { T4x16(SEb) }
      }
    }
    __syncthreads();   // barrier A: next panel seeded; ubP/stash complete
  }

  // ---- permutation parity via parallel inversion count (1024-thread map)
  int myinv = 0;
  {
    const int i0 = tid & 255;
    const int cbase = (tid >> 8) * 64;
    const int pi = perm[i0];
#pragma unroll 8
    for (int j = 0; j < 64; j++) {
      int jj = cbase + j;
      if (jj > i0 && perm[jj] < pi) myinv++;
    }
  }
#pragma unroll
  for (int off = 32; off; off >>= 1) myinv += __shfl_xor(myinv, off);
  if (L == 0) atomicAdd(&totinv, myinv);
  __syncthreads();
  if (tid == 0) out[blockIdx.x] = (float)((totinv & 1) ? -det : det);
}

extern "C" void kernel_launch(void* const* d_in, const int* in_sizes, int n_in,
                              void* d_out, int out_size, void* d_ws, size_t ws_size,
                              hipStream_t stream) {
  const float* x = (const float*)d_in[0];   // (1024, 512) fp32
  const float* F = (const float*)d_in[1];   // (512*512-512,) fp32
  float* out = (float*)d_out;               // (1024,) fp32
  const int B = out_size;                   // 1024
  hipLaunchKernelGGL(det_lu_kernel, dim3(B), dim3(1024), 0, stream, x, F, out);
}

// Round 23
// 906.549 us; speedup vs baseline: 1.0814x; 1.0168x over previous
//
#include <hip/hip_runtime.h>

#define NN 512
#define NM1 511
#define PCT(r, j) pcT[(r) * 13 + (j)]

// X-macros: T4x16(X) expands X(K,M) for K=0..3 (row group), M=0..15 (col)
#define T16(X, K) X(K,0) X(K,1) X(K,2) X(K,3) X(K,4) X(K,5) X(K,6) X(K,7) \
  X(K,8) X(K,9) X(K,10) X(K,11) X(K,12) X(K,13) X(K,14) X(K,15)
#define T4x16(X) T16(X,0) T16(X,1) T16(X,2) T16(X,3)
#define T16S(X) X(0) X(1) X(2) X(3) X(4) X(5) X(6) X(7) \
  X(8) X(9) X(10) X(11) X(12) X(13) X(14) X(15)
#define P8(X, K) X(K,0) X(K,1) X(K,2) X(K,3) X(K,4) X(K,5) X(K,6) X(K,7)
#define P4x8(X) P8(X,0) P8(X,1) P8(X,2) P8(X,3)

// readlane: value of v at (uniform) lane l -> scalar
__device__ __forceinline__ float rdlane(float v, int l) {
  return __uint_as_float(
      (unsigned)__builtin_amdgcn_readlane((int)__float_as_uint(v), l));
}
// fast reciprocal: v_rcp_f32 (~1 ulp); det still multiplies the EXACT pivot
__device__ __forceinline__ float fastrcp(float v) {
  float r;
  asm("v_rcp_f32 %0, %1" : "=v"(r) : "v"(v));
  return r;
}

// One block per matrix (1024 blocks), 1024 threads (16 waves), 1 block/CU via
// LDS pad + waves_per_eu(4,4) -> 128-reg budget.
// r23 = r22 lookahead (921us verified) + HALF-TUT seed path: the seed wave
// seeds only one 8-col half per panel, so its phase-2 early TUT runs only
// that half (256 FMAs, not 512). The hi half's missing TUT(2w-1) is applied
// in phase 1 of P=2w (new TUTHI arm); lo halves are dead after their seed.
// Column-lifetime trace: every col gets each rank-8 update exactly once.
// Nothing new lives across barriers (r15-r17 spill trigger avoided).
__global__ __attribute__((amdgpu_waves_per_eu(4, 4))) __launch_bounds__(1024)
void det_lu_kernel(
    const float* __restrict__ x,
    const float* __restrict__ F,
    float* __restrict__ out) {
  __shared__ __align__(16) float pcT[256 * 13];   // panel cols, row-major pad 13
  __shared__ __align__(16) float lbufD[2][8 * 256]; // multipliers (dbuf)
  __shared__ __align__(16) float UbufD[2][8 * 260]; // pivot rows (dbuf)
  __shared__ float livef[256];
  __shared__ int   perm[256];
  __shared__ int   upbuf[256];
  __shared__ int   dnbuf[256];
  __shared__ int   wavecnt[8];
  __shared__ int   totinv;
  __shared__ float ldspad[7900];    // LDS total > 80KiB -> exactly 1 block/CU

  const int tid = threadIdx.x;
  const int L   = tid & 63;       // lane
  const int w   = tid >> 6;       // wave, owns cols [16w, 16w+16)

  const float* xrow = x + (size_t)blockIdx.x * NN;

  // keep ldspad referenced (opaque never-true condition)
  if ((int)blockIdx.x < 0) ((volatile float*)ldspad)[tid] = 1.0f;

  // ---- rank the +/-1 pattern: up = x>0 positions, dn = x<=0 positions
  bool pos = false;
  unsigned long long mask = 0;
  if (tid < NN) {
    float xv = xrow[tid];
    pos = xv > 0.0f;
    mask = __ballot(pos);           // waves 0-7 fully active
    if (L == 0) wavecnt[w] = __popcll(mask);
  }
  if (tid == 0) totinv = 0;
  if (tid < 256) livef[tid] = 1.0f;
  __syncthreads();
  if (tid < NN) {
    int base = 0;
    for (int i = 0; i < w; i++) base += wavecnt[i];
    int pbelow = __popcll(mask & ((1ull << L) - 1ull));
    if (pos) upbuf[base + pbelow] = tid;
    else     dnbuf[(64 * w - base) + (L - pbelow)] = tid;
  }
  __syncthreads();

  // ---- gather tile into 64 named scalars: aK_M = sub[L+64K][16w+M]
#define DECLC(M) const int cg##M = dnbuf[16 * w + (M)];
  T16S(DECLC)
  const int rg0 = upbuf[L];
  const int rg1 = upbuf[L + 64];
  const int rg2 = upbuf[L + 128];
  const int rg3 = upbuf[L + 192];
#define DECLA(K, M)                                                         \
  float a##K##_##M = (cg##M == rg##K)                                       \
      ? 0.0f                                                                \
      : F[(size_t)rg##K * NM1 + cg##M - (cg##M > rg##K ? 1 : 0)];
  T4x16(DECLA)

  // ---- seed panel 0: wave 0 (owns cols 0..15) writes PCT[row][0..7]
  if (w == 0) {
#define S0(K, M) if ((M) < 8) PCT(L + 64 * (K), (M)) = a##K##_##M;
    T4x16(S0)
  }
  double det = 1.0;
  __syncthreads();   // barrier A (panel 0 seeded)

  // ======================= panel factor-step machinery (wave 0) ===========
#define DPPMAX(CTRL) {                                                      \
    unsigned _t = (unsigned)__builtin_amdgcn_update_dpp(                    \
        0, (int)key, (CTRL), 0xf, 0xf, false);                              \
    key = key > _t ? key : _t; }
#define BCJ(K, J, S) if ((J) >= (S)) uv##J = rdlane(pr##K##_##J, lp);
#define BCARM(K, S)                                                         \
    if (kp == (K)) { BCJ(K,0,S) BCJ(K,1,S) BCJ(K,2,S) BCJ(K,3,S)            \
                     BCJ(K,4,S) BCJ(K,5,S) BCJ(K,6,S) BCJ(K,7,S) }
#define LSTEP(K, S)                                                         \
    float l##K = ((dead4 >> (K)) & 1u) ? 0.0f : pr##K##_##S * invp;         \
    pr##K##_##S = l##K;
#define UPD(K, J, S)                                                        \
    if ((J) > (S)) pr##K##_##J = fmaf(-l##K, uv##J, pr##K##_##J);
#define UPDJ(J, S) UPD(0,J,S) UPD(1,J,S) UPD(2,J,S) UPD(3,J,S)
#define FSTEP(S) {                                                          \
    unsigned b0 = (dead4 & 1u) ? 0u                                         \
        : ((__float_as_uint(fabsf(pr0_##S)) & 0xFFFFFF00u) | (unsigned)L);  \
    unsigned b1 = (dead4 & 2u) ? 0u                                         \
        : ((__float_as_uint(fabsf(pr1_##S)) & 0xFFFFFF00u) | (unsigned)(L + 64)); \
    unsigned b2 = (dead4 & 4u) ? 0u                                         \
        : ((__float_as_uint(fabsf(pr2_##S)) & 0xFFFFFF00u) | (unsigned)(L + 128)); \
    unsigned b3 = (dead4 & 8u) ? 0u                                         \
        : ((__float_as_uint(fabsf(pr3_##S)) & 0xFFFFFF00u) | (unsigned)(L + 192)); \
    unsigned m01 = b0 > b1 ? b0 : b1, m23 = b2 > b3 ? b2 : b3;              \
    unsigned key = m01 > m23 ? m01 : m23;                                   \
    DPPMAX(0x111) DPPMAX(0x112) DPPMAX(0x114) DPPMAX(0x118)                 \
    DPPMAX(0x142) DPPMAX(0x143)                                             \
    const int pv = __builtin_amdgcn_readlane((int)key, 63) & 255;           \
    const int kp = pv >> 6, lp = pv & 63;                                   \
    if (lp == L) dead4 |= 1u << kp;                                         \
    float uv0 = 0.f, uv1 = 0.f, uv2 = 0.f, uv3 = 0.f;                       \
    float uv4 = 0.f, uv5 = 0.f, uv6 = 0.f, uv7 = 0.f;                       \
    BCARM(0,S) BCARM(1,S) BCARM(2,S) BCARM(3,S)                             \
    const float piv = uv##S;                                                \
    det *= (double)piv;                                                     \
    const float invp = fastrcp(piv);                                        \
    LSTEP(0,S) LSTEP(1,S) LSTEP(2,S) LSTEP(3,S)                             \
    UPDJ(0,S) UPDJ(1,S) UPDJ(2,S) UPDJ(3,S)                                 \
    UPDJ(4,S) UPDJ(5,S) UPDJ(6,S) UPDJ(7,S)                                 \
    lbP[(S) * 256 + L      ] = l0;                                          \
    lbP[(S) * 256 + L +  64] = l1;                                          \
    lbP[(S) * 256 + L + 128] = l2;                                          \
    lbP[(S) * 256 + L + 192] = l3;                                          \
    if (L == lp) livef[pv] = 0.0f;                                          \
    if (L == 0) perm[P * 8 + (S)] = pv;                                     \
  }

  // ---- post-barrier stash of raw pivot row T (own 16-col strip, into ubP)
#define STQW(T, K)                                                          \
    if (L == (p##T & 63)) {                                                 \
      float* ubw = &ubP[(T) * 260 + 16 * w];                                \
      *reinterpret_cast<float4*>(ubw + 0) =                                 \
          make_float4(a##K##_0, a##K##_1, a##K##_2, a##K##_3);              \
      *reinterpret_cast<float4*>(ubw + 4) =                                 \
          make_float4(a##K##_4, a##K##_5, a##K##_6, a##K##_7);              \
      *reinterpret_cast<float4*>(ubw + 8) =                                 \
          make_float4(a##K##_8, a##K##_9, a##K##_10, a##K##_11);            \
      *reinterpret_cast<float4*>(ubw + 12) =                                \
          make_float4(a##K##_12, a##K##_13, a##K##_14, a##K##_15);          \
    }
#define STASHT(T) {                                                         \
    const int kpt = p##T >> 6;                                              \
    if (kpt == 0)      { STQW(T, 0) }                                       \
    else if (kpt == 1) { STQW(T, 1) }                                       \
    else if (kpt == 2) { STQW(T, 2) }                                       \
    else               { STQW(T, 3) }                                       \
  }

  // trailing update body: A_K_M -= sum_t lk_K[t] * U[t][M]; quad-selectable
#define TUROW(K, A, B, C, D)                                                \
    a##K##_##A = fmaf(-lk##K, uq.x, a##K##_##A);                            \
    a##K##_##B = fmaf(-lk##K, uq.y, a##K##_##B);                            \
    a##K##_##C = fmaf(-lk##K, uq.z, a##K##_##C);                            \
    a##K##_##D = fmaf(-lk##K, uq.w, a##K##_##D);
#define TUQ(A, B, C, D)                                                     \
    TUROW(0, A, B, C, D) TUROW(1, A, B, C, D)                               \
    TUROW(2, A, B, C, D) TUROW(3, A, B, C, D)
#define TUTCORE(LB_, UB_, Q0_, Q1_, Q2_, Q3_)                               \
    _Pragma("unroll 2")                                                     \
    for (int t = 0; t < 8; t++) {                                           \
      const float lk0 = (LB_)[t * 256 + L];                                 \
      const float lk1 = (LB_)[t * 256 + L + 64];                            \
      const float lk2 = (LB_)[t * 256 + L + 128];                           \
      const float lk3 = (LB_)[t * 256 + L + 192];                           \
      const float* ub_ = &(UB_)[t * 260 + 16 * w];                          \
      if (Q0_) { const float4 uq = *reinterpret_cast<const float4*>(ub_ + 0);  \
        TUQ(0, 1, 2, 3) }                                                   \
      if (Q1_) { const float4 uq = *reinterpret_cast<const float4*>(ub_ + 4);  \
        TUQ(4, 5, 6, 7) }                                                   \
      if (Q2_) { const float4 uq = *reinterpret_cast<const float4*>(ub_ + 8);  \
        TUQ(8, 9, 10, 11) }                                                 \
      if (Q3_) { const float4 uq = *reinterpret_cast<const float4*>(ub_ + 12); \
        TUQ(12, 13, 14, 15) }                                               \
    }
#define TUTLOOP(LB_, UB_) TUTCORE(LB_, UB_, 1, 1, 1, 1)
#define TUTLO(LB_, UB_)   TUTCORE(LB_, UB_, 1, 1, 0, 0)
#define TUTHI(LB_, UB_)   TUTCORE(LB_, UB_, 0, 0, 1, 1)

  // ---- panel loop with lookahead (barriers at uniform top level ONLY)
#pragma unroll 1
  for (int P = 0; P < 32; P++) {
    const int bsel = P & 1;
    float* const lbP = lbufD[bsel];          // panel P multipliers
    float* const ubP = UbufD[bsel];          // panel P pivot rows
    const float* const lbQ = lbufD[bsel ^ 1]; // panel P-1
    const float* const ubQ = UbufD[bsel ^ 1];
    const bool trailingP = (2 * w + 1 > P);  // wave-uniform: live at P

    // -------- phase 1: factor(P) on wave 0 || deferred TUT(P-1) on others
    if (w == 0) {
#define LDP(K, J) float pr##K##_##J = PCT(L + 64 * (K), (J));
      P4x8(LDP)
      unsigned dead4 = 0u;
      FSTEP(0) FSTEP(1) FSTEP(2) FSTEP(3)
      FSTEP(4) FSTEP(5) FSTEP(6) FSTEP(7)
    } else if (P > 0 && w > (P >> 1)) {
      TUTLOOP(lbQ, ubQ)                  // plain trailing: full TUT(P-1)
    } else if (P > 0 && w == (P >> 1) && (P & 1) == 0) {
      TUTHI(lbQ, ubQ)                    // seed-wave leftover: hi half only
    }
    __syncthreads();   // barrier B: lbP/livef/perm visible; TUT(P-1) done

    // -------- phase 2: stash + per-wave U-solve (trailing waves);
    //                   seed wave: early HALF TUT(P) + seed panel P+1
    if (trailingP) {
      const int p0 = perm[P * 8 + 0], p1 = perm[P * 8 + 1];
      const int p2 = perm[P * 8 + 2], p3 = perm[P * 8 + 3];
      const int p4 = perm[P * 8 + 4], p5 = perm[P * 8 + 5];
      const int p6 = perm[P * 8 + 6], p7 = perm[P * 8 + 7];
      STASHT(0) STASHT(1) STASHT(2) STASHT(3)
      STASHT(4) STASHT(5) STASHT(6) STASHT(7)
      asm volatile("s_waitcnt lgkmcnt(0)" ::: "memory");
      if (L < 16) {            // per-wave U-solve on OWN 16-col strip
        const int jb = 16 * w + L;
        float u[8];
#pragma unroll
        for (int t = 0; t < 8; t++) {
          const int pt = perm[P * 8 + t];
          float acc = ubP[t * 260 + jb];
#pragma unroll
          for (int s2 = 0; s2 < t; s2++)
            acc = fmaf(-lbP[s2 * 256 + pt], u[s2], acc);
          u[t] = acc;
          ubP[t * 260 + jb] = acc;
        }
      }
      asm volatile("s_waitcnt lgkmcnt(0)" ::: "memory");
    }
    {
      const int wstar = (P + 1) >> 1, h = (P + 1) & 1;
      if (P < 31 && w == wstar) {        // seed wave is always trailingP
        const float lv0 = livef[L];
        const float lv1 = livef[L + 64];
        const float lv2 = livef[L + 128];
        const float lv3 = livef[L + 192];
#define SEa(K, M) if ((M) < 8)  PCT(L + 64*(K), (M))     = a##K##_##M * lv##K;
#define SEb(K, M) if ((M) >= 8) PCT(L + 64*(K), (M) - 8) = a##K##_##M * lv##K;
        if (h == 0) { TUTLO(lbP, ubP) T4x16(SEa) }
        else        { TUTHI(lbP, ubP) T4x16(SEb) }
      }
    }
    __syncthreads();   // barrier A: next panel seeded; ubP/stash complete
  }

  // ---- permutation parity via parallel inversion count (1024-thread map)
  int myinv = 0;
  {
    const int i0 = tid & 255;
    const int cbase = (tid >> 8) * 64;
    const int pi = perm[i0];
#pragma unroll 8
    for (int j = 0; j < 64; j++) {
      int jj = cbase + j;
      if (jj > i0 && perm[jj] < pi) myinv++;
    }
  }
#pragma unroll
  for (int off = 32; off; off >>= 1) myinv += __shfl_xor(myinv, off);
  if (L == 0) atomicAdd(&totinv, myinv);
  __syncthreads();
  if (tid == 0) out[blockIdx.x] = (float)((totinv & 1) ? -det : det);
}

extern "C" void kernel_launch(void* const* d_in, const int* in_sizes, int n_in,
                              void* d_out, int out_size, void* d_ws, size_t ws_size,
                              hipStream_t stream) {
  const float* x = (const float*)d_in[0];   // (1024, 512) fp32
  const float* F = (const float*)d_in[1];   // (512*512-512,) fp32
  float* out = (float*)d_out;               // (1024,) fp32
  const int B = out_size;                   // 1024
  hipLaunchKernelGGL(det_lu_kernel, dim3(B), dim3(1024), 0, stream, x, F, out);
}

// Round 24
// 905.376 us; speedup vs baseline: 1.0828x; 1.0013x over previous
//
#include <hip/hip_runtime.h>

#define NN 512
#define NM1 511
#define PCT(r, j) pcT[(r) * 13 + (j)]

// X-macros: T4x16(X) expands X(K,M) for K=0..3 (row group), M=0..15 (col)
#define T16(X, K) X(K,0) X(K,1) X(K,2) X(K,3) X(K,4) X(K,5) X(K,6) X(K,7) \
  X(K,8) X(K,9) X(K,10) X(K,11) X(K,12) X(K,13) X(K,14) X(K,15)
#define T4x16(X) T16(X,0) T16(X,1) T16(X,2) T16(X,3)
#define T16S(X) X(0) X(1) X(2) X(3) X(4) X(5) X(6) X(7) \
  X(8) X(9) X(10) X(11) X(12) X(13) X(14) X(15)
#define P8(X, K) X(K,0) X(K,1) X(K,2) X(K,3) X(K,4) X(K,5) X(K,6) X(K,7)
#define P4x8(X) P8(X,0) P8(X,1) P8(X,2) P8(X,3)

// readlane: value of v at (uniform) lane l -> scalar
__device__ __forceinline__ float rdlane(float v, int l) {
  return __uint_as_float(
      (unsigned)__builtin_amdgcn_readlane((int)__float_as_uint(v), l));
}
// fast reciprocal: v_rcp_f32 (~1 ulp); det still multiplies the EXACT pivot
__device__ __forceinline__ float fastrcp(float v) {
  float r;
  asm("v_rcp_f32 %0, %1" : "=v"(r) : "v"(v));
  return r;
}

// One block per matrix (1024 blocks), 1024 threads (16 waves), 1 block/CU via
// LDS pad + waves_per_eu(4,4) -> 128-reg budget.
// r24 = r23 (906us verified: lookahead + half-TUT seed) + T5 s_setprio on the
// two straggler waves: (phase 1) wave 0's serial factor chain competes for
// issue with 3 TUT waves on its SIMD — prio 1 during FSTEPs; (phase 2) the
// seed wave's stash->U-solve->half-TUT->seed chain — prio 1 for that span.
// T5 requires wave role diversity (m190 null on lockstep; m218b +21% with
// role split) — r22's lookahead created exactly that structure. Scheduling
// hint only: zero dataflow/liveness change vs r23.
__global__ __attribute__((amdgpu_waves_per_eu(4, 4))) __launch_bounds__(1024)
void det_lu_kernel(
    const float* __restrict__ x,
    const float* __restrict__ F,
    float* __restrict__ out) {
  __shared__ __align__(16) float pcT[256 * 13];   // panel cols, row-major pad 13
  __shared__ __align__(16) float lbufD[2][8 * 256]; // multipliers (dbuf)
  __shared__ __align__(16) float UbufD[2][8 * 260]; // pivot rows (dbuf)
  __shared__ float livef[256];
  __shared__ int   perm[256];
  __shared__ int   upbuf[256];
  __shared__ int   dnbuf[256];
  __shared__ int   wavecnt[8];
  __shared__ int   totinv;
  __shared__ float ldspad[7900];    // LDS total > 80KiB -> exactly 1 block/CU

  const int tid = threadIdx.x;
  const int L   = tid & 63;       // lane
  const int w   = tid >> 6;       // wave, owns cols [16w, 16w+16)

  const float* xrow = x + (size_t)blockIdx.x * NN;

  // keep ldspad referenced (opaque never-true condition)
  if ((int)blockIdx.x < 0) ((volatile float*)ldspad)[tid] = 1.0f;

  // ---- rank the +/-1 pattern: up = x>0 positions, dn = x<=0 positions
  bool pos = false;
  unsigned long long mask = 0;
  if (tid < NN) {
    float xv = xrow[tid];
    pos = xv > 0.0f;
    mask = __ballot(pos);           // waves 0-7 fully active
    if (L == 0) wavecnt[w] = __popcll(mask);
  }
  if (tid == 0) totinv = 0;
  if (tid < 256) livef[tid] = 1.0f;
  __syncthreads();
  if (tid < NN) {
    int base = 0;
    for (int i = 0; i < w; i++) base += wavecnt[i];
    int pbelow = __popcll(mask & ((1ull << L) - 1ull));
    if (pos) upbuf[base + pbelow] = tid;
    else     dnbuf[(64 * w - base) + (L - pbelow)] = tid;
  }
  __syncthreads();

  // ---- gather tile into 64 named scalars: aK_M = sub[L+64K][16w+M]
#define DECLC(M) const int cg##M = dnbuf[16 * w + (M)];
  T16S(DECLC)
  const int rg0 = upbuf[L];
  const int rg1 = upbuf[L + 64];
  const int rg2 = upbuf[L + 128];
  const int rg3 = upbuf[L + 192];
#define DECLA(K, M)                                                         \
  float a##K##_##M = (cg##M == rg##K)                                       \
      ? 0.0f                                                                \
      : F[(size_t)rg##K * NM1 + cg##M - (cg##M > rg##K ? 1 : 0)];
  T4x16(DECLA)

  // ---- seed panel 0: wave 0 (owns cols 0..15) writes PCT[row][0..7]
  if (w == 0) {
#define S0(K, M) if ((M) < 8) PCT(L + 64 * (K), (M)) = a##K##_##M;
    T4x16(S0)
  }
  double det = 1.0;
  __syncthreads();   // barrier A (panel 0 seeded)

  // ======================= panel factor-step machinery (wave 0) ===========
#define DPPMAX(CTRL) {                                                      \
    unsigned _t = (unsigned)__builtin_amdgcn_update_dpp(                    \
        0, (int)key, (CTRL), 0xf, 0xf, false);                              \
    key = key > _t ? key : _t; }
#define BCJ(K, J, S) if ((J) >= (S)) uv##J = rdlane(pr##K##_##J, lp);
#define BCARM(K, S)                                                         \
    if (kp == (K)) { BCJ(K,0,S) BCJ(K,1,S) BCJ(K,2,S) BCJ(K,3,S)            \
                     BCJ(K,4,S) BCJ(K,5,S) BCJ(K,6,S) BCJ(K,7,S) }
#define LSTEP(K, S)                                                         \
    float l##K = ((dead4 >> (K)) & 1u) ? 0.0f : pr##K##_##S * invp;         \
    pr##K##_##S = l##K;
#define UPD(K, J, S)                                                        \
    if ((J) > (S)) pr##K##_##J = fmaf(-l##K, uv##J, pr##K##_##J);
#define UPDJ(J, S) UPD(0,J,S) UPD(1,J,S) UPD(2,J,S) UPD(3,J,S)
#define FSTEP(S) {                                                          \
    unsigned b0 = (dead4 & 1u) ? 0u                                         \
        : ((__float_as_uint(fabsf(pr0_##S)) & 0xFFFFFF00u) | (unsigned)L);  \
    unsigned b1 = (dead4 & 2u) ? 0u                                         \
        : ((__float_as_uint(fabsf(pr1_##S)) & 0xFFFFFF00u) | (unsigned)(L + 64)); \
    unsigned b2 = (dead4 & 4u) ? 0u                                         \
        : ((__float_as_uint(fabsf(pr2_##S)) & 0xFFFFFF00u) | (unsigned)(L + 128)); \
    unsigned b3 = (dead4 & 8u) ? 0u                                         \
        : ((__float_as_uint(fabsf(pr3_##S)) & 0xFFFFFF00u) | (unsigned)(L + 192)); \
    unsigned m01 = b0 > b1 ? b0 : b1, m23 = b2 > b3 ? b2 : b3;              \
    unsigned key = m01 > m23 ? m01 : m23;                                   \
    DPPMAX(0x111) DPPMAX(0x112) DPPMAX(0x114) DPPMAX(0x118)                 \
    DPPMAX(0x142) DPPMAX(0x143)                                             \
    const int pv = __builtin_amdgcn_readlane((int)key, 63) & 255;           \
    const int kp = pv >> 6, lp = pv & 63;                                   \
    if (lp == L) dead4 |= 1u << kp;                                         \
    float uv0 = 0.f, uv1 = 0.f, uv2 = 0.f, uv3 = 0.f;                       \
    float uv4 = 0.f, uv5 = 0.f, uv6 = 0.f, uv7 = 0.f;                       \
    BCARM(0,S) BCARM(1,S) BCARM(2,S) BCARM(3,S)                             \
    const float piv = uv##S;                                                \
    det *= (double)piv;                                                     \
    const float invp = fastrcp(piv);                                        \
    LSTEP(0,S) LSTEP(1,S) LSTEP(2,S) LSTEP(3,S)                             \
    UPDJ(0,S) UPDJ(1,S) UPDJ(2,S) UPDJ(3,S)                                 \
    UPDJ(4,S) UPDJ(5,S) UPDJ(6,S) UPDJ(7,S)                                 \
    lbP[(S) * 256 + L      ] = l0;                                          \
    lbP[(S) * 256 + L +  64] = l1;                                          \
    lbP[(S) * 256 + L + 128] = l2;                                          \
    lbP[(S) * 256 + L + 192] = l3;                                          \
    if (L == lp) livef[pv] = 0.0f;                                          \
    if (L == 0) perm[P * 8 + (S)] = pv;                                     \
  }

  // ---- post-barrier stash of raw pivot row T (own 16-col strip, into ubP)
#define STQW(T, K)                                                          \
    if (L == (p##T & 63)) {                                                 \
      float* ubw = &ubP[(T) * 260 + 16 * w];                                \
      *reinterpret_cast<float4*>(ubw + 0) =                                 \
          make_float4(a##K##_0, a##K##_1, a##K##_2, a##K##_3);              \
      *reinterpret_cast<float4*>(ubw + 4) =                                 \
          make_float4(a##K##_4, a##K##_5, a##K##_6, a##K##_7);              \
      *reinterpret_cast<float4*>(ubw + 8) =                                 \
          make_float4(a##K##_8, a##K##_9, a##K##_10, a##K##_11);            \
      *reinterpret_cast<float4*>(ubw + 12) =                                \
          make_float4(a##K##_12, a##K##_13, a##K##_14, a##K##_15);          \
    }
#define STASHT(T) {                                                         \
    const int kpt = p##T >> 6;                                              \
    if (kpt == 0)      { STQW(T, 0) }                                       \
    else if (kpt == 1) { STQW(T, 1) }                                       \
    else if (kpt == 2) { STQW(T, 2) }                                       \
    else               { STQW(T, 3) }                                       \
  }

  // trailing update body: A_K_M -= sum_t lk_K[t] * U[t][M]; quad-selectable
#define TUROW(K, A, B, C, D)                                                \
    a##K##_##A = fmaf(-lk##K, uq.x, a##K##_##A);                            \
    a##K##_##B = fmaf(-lk##K, uq.y, a##K##_##B);                            \
    a##K##_##C = fmaf(-lk##K, uq.z, a##K##_##C);                            \
    a##K##_##D = fmaf(-lk##K, uq.w, a##K##_##D);
#define TUQ(A, B, C, D)                                                     \
    TUROW(0, A, B, C, D) TUROW(1, A, B, C, D)                               \
    TUROW(2, A, B, C, D) TUROW(3, A, B, C, D)
#define TUTCORE(LB_, UB_, Q0_, Q1_, Q2_, Q3_)                               \
    _Pragma("unroll 2")                                                     \
    for (int t = 0; t < 8; t++) {                                           \
      const float lk0 = (LB_)[t * 256 + L];                                 \
      const float lk1 = (LB_)[t * 256 + L + 64];                            \
      const float lk2 = (LB_)[t * 256 + L + 128];                           \
      const float lk3 = (LB_)[t * 256 + L + 192];                           \
      const float* ub_ = &(UB_)[t * 260 + 16 * w];                          \
      if (Q0_) { const float4 uq = *reinterpret_cast<const float4*>(ub_ + 0);  \
        TUQ(0, 1, 2, 3) }                                                   \
      if (Q1_) { const float4 uq = *reinterpret_cast<const float4*>(ub_ + 4);  \
        TUQ(4, 5, 6, 7) }                                                   \
      if (Q2_) { const float4 uq = *reinterpret_cast<const float4*>(ub_ + 8);  \
        TUQ(8, 9, 10, 11) }                                                 \
      if (Q3_) { const float4 uq = *reinterpret_cast<const float4*>(ub_ + 12); \
        TUQ(12, 13, 14, 15) }                                               \
    }
#define TUTLOOP(LB_, UB_) TUTCORE(LB_, UB_, 1, 1, 1, 1)
#define TUTLO(LB_, UB_)   TUTCORE(LB_, UB_, 1, 1, 0, 0)
#define TUTHI(LB_, UB_)   TUTCORE(LB_, UB_, 0, 0, 1, 1)

  // ---- panel loop with lookahead (barriers at uniform top level ONLY)
#pragma unroll 1
  for (int P = 0; P < 32; P++) {
    const int bsel = P & 1;
    float* const lbP = lbufD[bsel];          // panel P multipliers
    float* const ubP = UbufD[bsel];          // panel P pivot rows
    const float* const lbQ = lbufD[bsel ^ 1]; // panel P-1
    const float* const ubQ = UbufD[bsel ^ 1];
    const bool trailingP = (2 * w + 1 > P);  // wave-uniform: live at P

    // -------- phase 1: factor(P) on wave 0 || deferred TUT(P-1) on others
    if (w == 0) {
      __builtin_amdgcn_s_setprio(1);   // critical serial chain
#define LDP(K, J) float pr##K##_##J = PCT(L + 64 * (K), (J));
      P4x8(LDP)
      unsigned dead4 = 0u;
      FSTEP(0) FSTEP(1) FSTEP(2) FSTEP(3)
      FSTEP(4) FSTEP(5) FSTEP(6) FSTEP(7)
      __builtin_amdgcn_s_setprio(0);
    } else if (P > 0 && w > (P >> 1)) {
      TUTLOOP(lbQ, ubQ)                  // plain trailing: full TUT(P-1)
    } else if (P > 0 && w == (P >> 1) && (P & 1) == 0) {
      TUTHI(lbQ, ubQ)                    // seed-wave leftover: hi half only
    }
    __syncthreads();   // barrier B: lbP/livef/perm visible; TUT(P-1) done

    // -------- phase 2: stash + per-wave U-solve (trailing waves);
    //                   seed wave: early HALF TUT(P) + seed panel P+1
    const int wstar = (P + 1) >> 1;
    const bool isSeed = (P < 31 && w == wstar);   // wave-uniform
    if (isSeed) __builtin_amdgcn_s_setprio(1);    // phase-2 straggler
    if (trailingP) {
      const int p0 = perm[P * 8 + 0], p1 = perm[P * 8 + 1];
      const int p2 = perm[P * 8 + 2], p3 = perm[P * 8 + 3];
      const int p4 = perm[P * 8 + 4], p5 = perm[P * 8 + 5];
      const int p6 = perm[P * 8 + 6], p7 = perm[P * 8 + 7];
      STASHT(0) STASHT(1) STASHT(2) STASHT(3)
      STASHT(4) STASHT(5) STASHT(6) STASHT(7)
      asm volatile("s_waitcnt lgkmcnt(0)" ::: "memory");
      if (L < 16) {            // per-wave U-solve on OWN 16-col strip
        const int jb = 16 * w + L;
        float u[8];
#pragma unroll
        for (int t = 0; t < 8; t++) {
          const int pt = perm[P * 8 + t];
          float acc = ubP[t * 260 + jb];
#pragma unroll
          for (int s2 = 0; s2 < t; s2++)
            acc = fmaf(-lbP[s2 * 256 + pt], u[s2], acc);
          u[t] = acc;
          ubP[t * 260 + jb] = acc;
        }
      }
      asm volatile("s_waitcnt lgkmcnt(0)" ::: "memory");
    }
    {
      const int h = (P + 1) & 1;
      if (isSeed) {                      // seed wave is always trailingP
        const float lv0 = livef[L];
        const float lv1 = livef[L + 64];
        const float lv2 = livef[L + 128];
        const float lv3 = livef[L + 192];
#define SEa(K, M) if ((M) < 8)  PCT(L + 64*(K), (M))     = a##K##_##M * lv##K;
#define SEb(K, M) if ((M) >= 8) PCT(L + 64*(K), (M) - 8) = a##K##_##M * lv##K;
        if (h == 0) { TUTLO(lbP, ubP) T4x16(SEa) }
        else        { TUTHI(lbP, ubP) T4x16(SEb) }
        __builtin_amdgcn_s_setprio(0);
      }
    }
    __syncthreads();   // barrier A: next panel seeded; ubP/stash complete
  }

  // ---- permutation parity via parallel inversion count (1024-thread map)
  int myinv = 0;
  {
    const int i0 = tid & 255;
    const int cbase = (tid >> 8) * 64;
    const int pi = perm[i0];
#pragma unroll 8
    for (int j = 0; j < 64; j++) {
      int jj = cbase + j;
      if (jj > i0 && perm[jj] < pi) myinv++;
    }
  }
#pragma unroll
  for (int off = 32; off; off >>= 1) myinv += __shfl_xor(myinv, off);
  if (L == 0) atomicAdd(&totinv, myinv);
  __syncthreads();
  if (tid == 0) out[blockIdx.x] = (float)((totinv & 1) ? -det : det);
}

extern "C" void kernel_launch(void* const* d_in, const int* in_sizes, int n_in,
                              void* d_out, int out_size, void* d_ws, size_t ws_size,
                              hipStream_t stream) {
  const float* x = (const float*)d_in[0];   // (1024, 512) fp32
  const float* F = (const float*)d_in[1];   // (512*512-512,) fp32
  float* out = (float*)d_out;               // (1024,) fp32
  const int B = out_size;                   // 1024
  hipLaunchKernelGGL(det_lu_kernel, dim3(B), dim3(1024), 0, stream, x, F, out);
}